// Round 8
// baseline (208.280 us; speedup 1.0000x reference)
//
#include <hip/hip_runtime.h>
#include <stdint.h>

typedef unsigned short ushortT;

#define NROWS 131072
#define DIM 64
#define KCODES 1024
#define NSEG 6
#define KTOT (NSEG * DIM)   // 384
#define NKC (KTOT / 32)     // 12 K-chunks of 32
#define MT 64               // rows per block
#define NTC 256             // codes per code-iter (4 waves x 64)
#define CI (KCODES / NTC)   // 4 code iters
#define KCSTEP (4 * KCODES * 8)  // ushort elements per kc plane = 32768

typedef float f32x4 __attribute__((ext_vector_type(4)));
typedef short bf16x8 __attribute__((ext_vector_type(8)));

__device__ __forceinline__ ushortT f2bf(float f) {
  union { float f; uint32_t u; } v; v.f = f;
  return (ushortT)((v.u + 0x7FFFu + ((v.u >> 16) & 1u)) >> 16);  // RNE
}
__device__ __forceinline__ float bf2f(ushortT b) {
  union { float f; uint32_t u; } v; v.u = ((uint32_t)b) << 16;
  return v.f;
}

// Expand codebook: 3-level bf16 split, frag-major layout Bg[(kc*4+q)*1024+code][8],
// segment planes along K: sB = {e0,e1,e2,e0,e1,e0}. Also h2[k]=0.5*||e_k||^2 (fp32).
__global__ __launch_bounds__(256) void vq_prep(const float* __restrict__ emb,
                                               ushortT* __restrict__ Bg,
                                               float* __restrict__ h2) {
  const int code = blockIdx.x * 256 + threadIdx.x;
  float e[DIM];
  float s = 0.f;
#pragma unroll
  for (int d = 0; d < DIM; ++d) {
    e[d] = emb[d * KCODES + code];
    s = fmaf(e[d], e[d], s);
  }
  h2[code] = 0.5f * s;
#pragma unroll
  for (int d = 0; d < DIM; ++d) {
    ushortT p0 = f2bf(e[d]); float r1 = e[d] - bf2f(p0);   // exact (Sterbenz)
    ushortT p1 = f2bf(r1);   float r2 = r1 - bf2f(p1);     // exact
    ushortT p2 = f2bf(r2);
    const ushortT pv[3] = {p0, p1, p2};
    const int sB[6] = {0, 1, 2, 0, 1, 0};
#pragma unroll
    for (int seg = 0; seg < 6; ++seg) {
      int k = seg * DIM + d;
      int kc = k >> 5, q = (k >> 3) & 3, j = k & 7;
      Bg[((size_t)((kc * 4 + q) * KCODES + code)) * 8 + j] = pv[sB[seg]];
    }
  }
}

// Block: 64 rows x 1024 codes. A staged once frag-major in LDS; B global->VGPR
// (L2-hot), barrier-free K-loop. K-loop = 6 pairs with ping-pong b0/b1 register
// sets: in-place reload right after consumption gives 2-iter prefetch distance
// (~450 cyc slack > L2 latency) and ZERO register copies; addresses are two
// pointers bumped by constants (R7 burned ~39 VALU/iter on addr math + moves).
__global__ __launch_bounds__(256, 2) void vq_main(const float* __restrict__ x,
                                                  const ushortT* __restrict__ Bg,
                                                  const float* __restrict__ h2,
                                                  const float* __restrict__ emb,
                                                  float* __restrict__ out) {
  __shared__ ushortT A_lds[NKC * 4 * MT * 8];  // 48 KB  [kc][quad][row][8]
  __shared__ float bvs[4][MT];
  __shared__ int bis[4][MT];
  __shared__ int widx_s[MT];

  const int tid = threadIdx.x;
  const int wave = tid >> 6, lane = tid & 63, quad = lane >> 4, lq = lane & 15;
  const size_t rowbase = (size_t)blockIdx.x * MT;

  // ---- stage A: x rows -> 3 bf16 planes, frag-major. thread: row=tid>>2, 16 d's ----
  {
    const int row = tid >> 2, dg = (tid & 3) << 4;
    const float4* xr = (const float4*)(x + (rowbase + row) * DIM + dg);
    float v[16];
#pragma unroll
    for (int i = 0; i < 4; ++i) {
      float4 t = xr[i];
      v[4 * i] = t.x; v[4 * i + 1] = t.y; v[4 * i + 2] = t.z; v[4 * i + 3] = t.w;
    }
    ushortT pl[3][16];
#pragma unroll
    for (int i = 0; i < 16; ++i) {
      ushortT a0 = f2bf(v[i]); float r1 = v[i] - bf2f(a0);
      ushortT a1 = f2bf(r1);   float r2 = r1 - bf2f(a1);
      pl[0][i] = a0; pl[1][i] = a1; pl[2][i] = f2bf(r2);
    }
    const int sA[6] = {0, 0, 0, 1, 1, 2};  // x-plane per segment
    const int q0 = (dg & 31) >> 3;         // 0 or 2
#pragma unroll
    for (int seg = 0; seg < 6; ++seg) {
      int kc = seg * 2 + (dg >> 5);
      *(uint4*)&A_lds[(((kc * 4 + q0) * MT) + row) * 8]     = *(uint4*)&pl[sA[seg]][0];
      *(uint4*)&A_lds[(((kc * 4 + q0 + 1) * MT) + row) * 8] = *(uint4*)&pl[sA[seg]][8];
    }
  }
  __syncthreads();  // A_lds ready; only block-wide barrier before epilogue

  float bestv[4][4];
  int besti[4][4];
#pragma unroll
  for (int i = 0; i < 4; ++i)
#pragma unroll
    for (int r = 0; r < 4; ++r) { bestv[i][r] = 3.4e38f; besti[i][r] = 0; }

#pragma unroll 1
  for (int ci = 0; ci < CI; ++ci) {
    const int codeBase = ci * NTC;
    f32x4 acc[4][4];
#pragma unroll
    for (int i = 0; i < 4; ++i)
#pragma unroll
      for (int j = 0; j < 4; ++j) acc[i][j] = (f32x4){0.f, 0.f, 0.f, 0.f};

    // lane's B base (kc=0) and A base for this ci
    const ushortT* bp0 =
        Bg + ((size_t)(quad * KCODES + codeBase + wave * 64 + lq)) * 8;
    const ushortT* ab = &A_lds[((quad * MT) + lq) * 8];

    bf16x8 b0[4], b1[4];
#pragma unroll
    for (int j = 0; j < 4; ++j) b0[j] = *(const bf16x8*)(bp0 + j * 128);
#pragma unroll
    for (int j = 0; j < 4; ++j) b1[j] = *(const bf16x8*)(bp0 + KCSTEP + j * 128);
    const ushortT* bp2 = bp0 + 2 * KCSTEP;  // even-kc prefetch pointer

#pragma unroll 1
    for (int p = 0; p < 6; ++p) {
      bf16x8 a0[4], a1[4];
#pragma unroll
      for (int i = 0; i < 4; ++i) {
        a0[i] = *(const bf16x8*)(ab + i * 128);         // kc=2p,  imm offs 0..768B
        a1[i] = *(const bf16x8*)(ab + 2048 + i * 128);  // kc=2p+1, +4096B
      }
#pragma unroll
      for (int i = 0; i < 4; ++i)
#pragma unroll
        for (int j = 0; j < 4; ++j)
          acc[i][j] = __builtin_amdgcn_mfma_f32_16x16x32_bf16(a0[i], b0[j], acc[i][j], 0, 0, 0);
      {
        const ushortT* pe = (p < 5) ? bp2 : bp0;  // last pair: harmless self-reload
#pragma unroll
        for (int j = 0; j < 4; ++j) b0[j] = *(const bf16x8*)(pe + j * 128);
      }
#pragma unroll
      for (int i = 0; i < 4; ++i)
#pragma unroll
        for (int j = 0; j < 4; ++j)
          acc[i][j] = __builtin_amdgcn_mfma_f32_16x16x32_bf16(a1[i], b1[j], acc[i][j], 0, 0, 0);
      {
        const ushortT* po = (p < 5) ? (bp2 + KCSTEP) : bp0;
#pragma unroll
        for (int j = 0; j < 4; ++j) b1[j] = *(const bf16x8*)(po + j * 128);
      }
      bp2 += 2 * KCSTEP;
      ab += 4096;  // 2 kc planes = 8192 B
    }

    // epilogue: val = 0.5||e||^2 - f.e ; merge into per-row running best
    float h2v[4];
#pragma unroll
    for (int j = 0; j < 4; ++j) h2v[j] = h2[codeBase + wave * 64 + j * 16 + lq];
#pragma unroll
    for (int i = 0; i < 4; ++i)
#pragma unroll
      for (int j = 0; j < 4; ++j) {
        const int idx = codeBase + wave * 64 + j * 16 + lq;
#pragma unroll
        for (int r = 0; r < 4; ++r) {
          float val = h2v[j] - acc[i][j][r];
          if (val < bestv[i][r]) { bestv[i][r] = val; besti[i][r] = idx; }  // idx ascending in (ci,j): strict < keeps lowest
        }
      }
  }

  // reduce across the 16 lanes sharing a quad (lane bits 0-3), lexicographic (val, idx)
#pragma unroll
  for (int m = 1; m < 16; m <<= 1) {
#pragma unroll
    for (int i = 0; i < 4; ++i)
#pragma unroll
      for (int r = 0; r < 4; ++r) {
        float ov = __shfl_xor(bestv[i][r], m, 64);
        int oi = __shfl_xor(besti[i][r], m, 64);
        if (ov < bestv[i][r] || (ov == bestv[i][r] && oi < besti[i][r])) {
          bestv[i][r] = ov; besti[i][r] = oi;
        }
      }
  }
  if (lq == 0) {
#pragma unroll
    for (int i = 0; i < 4; ++i)
#pragma unroll
      for (int r = 0; r < 4; ++r) {
        int row = i * 16 + quad * 4 + r;
        bvs[wave][row] = bestv[i][r];
        bis[wave][row] = besti[i][r];
      }
  }
  __syncthreads();
  if (tid < MT) {
    float bv = bvs[0][tid]; int bi = bis[0][tid];
#pragma unroll
    for (int w = 1; w < 4; ++w) {
      float ov = bvs[w][tid]; int oi = bis[w][tid];
      if (ov < bv || (ov == bv && oi < bi)) { bv = ov; bi = oi; }
    }
    widx_s[tid] = bi;
  }
  __syncthreads();
  // cooperative gather: thread handles row=tid>>2, 16 d's; emb is L2-resident (256KB)
  {
    const int row = tid >> 2, dg = (tid & 3) << 4;
    const int wi = widx_s[row];
    float4* o = (float4*)(out + (rowbase + row) * DIM + dg);
#pragma unroll
    for (int i = 0; i < 4; ++i) {
      float4 t;
      t.x = emb[(dg + 4 * i + 0) * KCODES + wi];
      t.y = emb[(dg + 4 * i + 1) * KCODES + wi];
      t.z = emb[(dg + 4 * i + 2) * KCODES + wi];
      t.w = emb[(dg + 4 * i + 3) * KCODES + wi];
      o[i] = t;
    }
  }
}

extern "C" void kernel_launch(void* const* d_in, const int* in_sizes, int n_in,
                              void* d_out, int out_size, void* d_ws, size_t ws_size,
                              hipStream_t stream) {
  const float* x = (const float*)d_in[0];
  const float* emb = (const float*)d_in[1];
  float* out = (float*)d_out;

  ushortT* Bg = (ushortT*)d_ws;               // 12*4*1024*8 ushort = 768 KB
  float* h2 = (float*)(Bg + NKC * 4 * KCODES * 8);  // 4 KB

  vq_prep<<<KCODES / 256, 256, 0, stream>>>(emb, Bg, h2);
  vq_main<<<NROWS / MT, 256, 0, stream>>>(x, Bg, h2, emb, out);
}

// Round 9
// 196.359 us; speedup vs baseline: 1.0607x; 1.0607x over previous
//
#include <hip/hip_runtime.h>
#include <stdint.h>

typedef unsigned short ushortT;

#define NROWS 131072
#define DIM 64
#define KCODES 1024
#define NSEG 6
#define KTOT (NSEG * DIM)   // 384
#define NKC (KTOT / 32)     // 12 K-chunks of 32
#define MT 64               // rows per block
#define NTC 256             // codes per code-iter (4 waves x 64)
#define CI (KCODES / NTC)   // 4 code iters
#define KCSTEP (4 * KCODES * 8)  // ushort elements per kc plane = 32768

typedef float f32x4 __attribute__((ext_vector_type(4)));
typedef short bf16x8 __attribute__((ext_vector_type(8)));

__device__ __forceinline__ ushortT f2bf(float f) {
  union { float f; uint32_t u; } v; v.f = f;
  return (ushortT)((v.u + 0x7FFFu + ((v.u >> 16) & 1u)) >> 16);  // RNE
}
__device__ __forceinline__ float bf2f(ushortT b) {
  union { float f; uint32_t u; } v; v.u = ((uint32_t)b) << 16;
  return v.f;
}

// Expand codebook: 3-level bf16 split, frag-major layout Bg[(kc*4+q)*1024+code][8],
// segment planes along K: sB = {e0,e1,e2,e0,e1,e0}. Also h2[k]=0.5*||e_k||^2 (fp32).
__global__ __launch_bounds__(256) void vq_prep(const float* __restrict__ emb,
                                               ushortT* __restrict__ Bg,
                                               float* __restrict__ h2) {
  const int code = blockIdx.x * 256 + threadIdx.x;
  float e[DIM];
  float s = 0.f;
#pragma unroll
  for (int d = 0; d < DIM; ++d) {
    e[d] = emb[d * KCODES + code];
    s = fmaf(e[d], e[d], s);
  }
  h2[code] = 0.5f * s;
#pragma unroll
  for (int d = 0; d < DIM; ++d) {
    ushortT p0 = f2bf(e[d]); float r1 = e[d] - bf2f(p0);   // exact (Sterbenz)
    ushortT p1 = f2bf(r1);   float r2 = r1 - bf2f(p1);     // exact
    ushortT p2 = f2bf(r2);
    const ushortT pv[3] = {p0, p1, p2};
    const int sB[6] = {0, 1, 2, 0, 1, 0};
#pragma unroll
    for (int seg = 0; seg < 6; ++seg) {
      int k = seg * DIM + d;
      int kc = k >> 5, q = (k >> 3) & 3, j = k & 7;
      Bg[((size_t)((kc * 4 + q) * KCODES + code)) * 8 + j] = pv[sB[seg]];
    }
  }
}

// Block: 64 rows x 1024 codes. A staged once frag-major in LDS; B global->VGPR
// (L2-hot), barrier-free K-loop. K-loop = 3 groups of 4 kc with a 4-deep
// in-place register rotation b[0..3]: consume b[s], reload b[s] from kc+4.
// Prefetch distance = 48 MFMA (~230-460 cyc) > L2 latency (~200-300 cyc);
// per-register scoreboard waits become fine-grained (never drain to 0).
// unroll 1 on the group loop pins register pressure (R5/R6 spill lesson).
__global__ __launch_bounds__(256, 2) void vq_main(const float* __restrict__ x,
                                                  const ushortT* __restrict__ Bg,
                                                  const float* __restrict__ h2,
                                                  const float* __restrict__ emb,
                                                  float* __restrict__ out) {
  __shared__ ushortT A_lds[NKC * 4 * MT * 8];  // 48 KB  [kc][quad][row][8]
  __shared__ float bvs[4][MT];
  __shared__ int bis[4][MT];
  __shared__ int widx_s[MT];

  const int tid = threadIdx.x;
  const int wave = tid >> 6, lane = tid & 63, quad = lane >> 4, lq = lane & 15;
  const size_t rowbase = (size_t)blockIdx.x * MT;

  // ---- stage A: x rows -> 3 bf16 planes, frag-major. thread: row=tid>>2, 16 d's ----
  {
    const int row = tid >> 2, dg = (tid & 3) << 4;
    const float4* xr = (const float4*)(x + (rowbase + row) * DIM + dg);
    float v[16];
#pragma unroll
    for (int i = 0; i < 4; ++i) {
      float4 t = xr[i];
      v[4 * i] = t.x; v[4 * i + 1] = t.y; v[4 * i + 2] = t.z; v[4 * i + 3] = t.w;
    }
    ushortT pl[3][16];
#pragma unroll
    for (int i = 0; i < 16; ++i) {
      ushortT a0 = f2bf(v[i]); float r1 = v[i] - bf2f(a0);
      ushortT a1 = f2bf(r1);   float r2 = r1 - bf2f(a1);
      pl[0][i] = a0; pl[1][i] = a1; pl[2][i] = f2bf(r2);
    }
    const int sA[6] = {0, 0, 0, 1, 1, 2};  // x-plane per segment
    const int q0 = (dg & 31) >> 3;         // 0 or 2
#pragma unroll
    for (int seg = 0; seg < 6; ++seg) {
      int kc = seg * 2 + (dg >> 5);
      *(uint4*)&A_lds[(((kc * 4 + q0) * MT) + row) * 8]     = *(uint4*)&pl[sA[seg]][0];
      *(uint4*)&A_lds[(((kc * 4 + q0 + 1) * MT) + row) * 8] = *(uint4*)&pl[sA[seg]][8];
    }
  }
  __syncthreads();  // A_lds ready; only block-wide barrier before epilogue

  float bestv[4][4];
  int besti[4][4];
#pragma unroll
  for (int i = 0; i < 4; ++i)
#pragma unroll
    for (int r = 0; r < 4; ++r) { bestv[i][r] = 3.4e38f; besti[i][r] = 0; }

#pragma unroll 1
  for (int ci = 0; ci < CI; ++ci) {
    const int codeBase = ci * NTC;
    f32x4 acc[4][4];
#pragma unroll
    for (int i = 0; i < 4; ++i)
#pragma unroll
      for (int j = 0; j < 4; ++j) acc[i][j] = (f32x4){0.f, 0.f, 0.f, 0.f};

    // lane's B base (kc=0) and A base for this ci
    const ushortT* bp0 =
        Bg + ((size_t)(quad * KCODES + codeBase + wave * 64 + lq)) * 8;
    const ushortT* ab = &A_lds[((quad * MT) + lq) * 8];

    // 4-deep rotation: b[s] holds kc = g*4 + s
    bf16x8 b[4][4];
#pragma unroll
    for (int s = 0; s < 4; ++s)
#pragma unroll
      for (int j = 0; j < 4; ++j)
        b[s][j] = *(const bf16x8*)(bp0 + (size_t)s * KCSTEP + j * 128);

    const ushortT* bpre = bp0 + 4 * (size_t)KCSTEP;

#pragma unroll 1
    for (int g = 0; g < 3; ++g) {
      const ushortT* pre = (g < 2) ? bpre : bp0;  // last group: harmless self-range reload
#pragma unroll
      for (int s = 0; s < 4; ++s) {
        bf16x8 a[4];
#pragma unroll
        for (int i = 0; i < 4; ++i)
          a[i] = *(const bf16x8*)(ab + s * 2048 + i * 128);
#pragma unroll
        for (int i = 0; i < 4; ++i)
#pragma unroll
          for (int j = 0; j < 4; ++j)
            acc[i][j] = __builtin_amdgcn_mfma_f32_16x16x32_bf16(a[i], b[s][j], acc[i][j], 0, 0, 0);
        // reload this set from kc+4 (in-place: WAR keeps it after the MFMAs)
#pragma unroll
        for (int j = 0; j < 4; ++j)
          b[s][j] = *(const bf16x8*)(pre + (size_t)s * KCSTEP + j * 128);
      }
      bpre += 4 * (size_t)KCSTEP;
      ab += 4 * 2048;
    }

    // epilogue: val = 0.5||e||^2 - f.e ; merge into per-row running best
    float h2v[4];
#pragma unroll
    for (int j = 0; j < 4; ++j) h2v[j] = h2[codeBase + wave * 64 + j * 16 + lq];
#pragma unroll
    for (int i = 0; i < 4; ++i)
#pragma unroll
      for (int j = 0; j < 4; ++j) {
        const int idx = codeBase + wave * 64 + j * 16 + lq;
#pragma unroll
        for (int r = 0; r < 4; ++r) {
          float val = h2v[j] - acc[i][j][r];
          if (val < bestv[i][r]) { bestv[i][r] = val; besti[i][r] = idx; }  // idx ascending in (ci,j): strict < keeps lowest
        }
      }
  }

  // reduce across the 16 lanes sharing a quad (lane bits 0-3), lexicographic (val, idx)
#pragma unroll
  for (int m = 1; m < 16; m <<= 1) {
#pragma unroll
    for (int i = 0; i < 4; ++i)
#pragma unroll
      for (int r = 0; r < 4; ++r) {
        float ov = __shfl_xor(bestv[i][r], m, 64);
        int oi = __shfl_xor(besti[i][r], m, 64);
        if (ov < bestv[i][r] || (ov == bestv[i][r] && oi < besti[i][r])) {
          bestv[i][r] = ov; besti[i][r] = oi;
        }
      }
  }
  if (lq == 0) {
#pragma unroll
    for (int i = 0; i < 4; ++i)
#pragma unroll
      for (int r = 0; r < 4; ++r) {
        int row = i * 16 + quad * 4 + r;
        bvs[wave][row] = bestv[i][r];
        bis[wave][row] = besti[i][r];
      }
  }
  __syncthreads();
  if (tid < MT) {
    float bv = bvs[0][tid]; int bi = bis[0][tid];
#pragma unroll
    for (int w = 1; w < 4; ++w) {
      float ov = bvs[w][tid]; int oi = bis[w][tid];
      if (ov < bv || (ov == bv && oi < bi)) { bv = ov; bi = oi; }
    }
    widx_s[tid] = bi;
  }
  __syncthreads();
  // cooperative gather: thread handles row=tid>>2, 16 d's; emb is L2-resident (256KB)
  {
    const int row = tid >> 2, dg = (tid & 3) << 4;
    const int wi = widx_s[row];
    float4* o = (float4*)(out + (rowbase + row) * DIM + dg);
#pragma unroll
    for (int i = 0; i < 4; ++i) {
      float4 t;
      t.x = emb[(dg + 4 * i + 0) * KCODES + wi];
      t.y = emb[(dg + 4 * i + 1) * KCODES + wi];
      t.z = emb[(dg + 4 * i + 2) * KCODES + wi];
      t.w = emb[(dg + 4 * i + 3) * KCODES + wi];
      o[i] = t;
    }
  }
}

extern "C" void kernel_launch(void* const* d_in, const int* in_sizes, int n_in,
                              void* d_out, int out_size, void* d_ws, size_t ws_size,
                              hipStream_t stream) {
  const float* x = (const float*)d_in[0];
  const float* emb = (const float*)d_in[1];
  float* out = (float*)d_out;

  ushortT* Bg = (ushortT*)d_ws;               // 12*4*1024*8 ushort = 768 KB
  float* h2 = (float*)(Bg + NKC * 4 * KCODES * 8);  // 4 KB

  vq_prep<<<KCODES / 256, 256, 0, stream>>>(emb, Bg, h2);
  vq_main<<<NROWS / MT, 256, 0, stream>>>(x, Bg, h2, emb, out);
}